// Round 4
// baseline (341.067 us; speedup 1.0000x reference)
//
#include <hip/hip_runtime.h>
#include <math.h>

#define T_STEPS 256
#define Fdim 32
#define Udim 64
#define G4 256            // 4*U
#define OUT_STEPS 24
#define ROWS 16           // batch rows per block (= MFMA N)
#define NBLK 256          // 4096 / 16
#define NTHR 256          // 4 waves, 1 wave/SIMD: minimal LDS traffic + barrier width,
                          // per-SIMD issue totals unchanged (4 cells/lane, ILP=4)
#define HBS 72            // row stride in shorts (144 B, 36 dwords: measured-best layout)
#define CHUNK 16
#define NCHUNK 16         // 16 * 16 = 256 steps
#define LOG2E 1.4426950408889634f

typedef __attribute__((ext_vector_type(8))) short short8;   // 8 bf16 = 4 VGPR
typedef __attribute__((ext_vector_type(4))) float f32x4;

__device__ __forceinline__ short f2bf(float f) {
    union { float f; unsigned u; } v; v.f = f;
    unsigned r = v.u + 0x7FFFu + ((v.u >> 16) & 1u);   // RNE
    return (short)(r >> 16);
}
__device__ __forceinline__ float bf2f(short s) {
    union { unsigned u; float f; } v; v.u = ((unsigned)(unsigned short)s) << 16;
    return v.f;
}
__device__ __forceinline__ float frcp(float v) { return __builtin_amdgcn_rcpf(v); }
__device__ __forceinline__ float fexp2(float v) { return __builtin_amdgcn_exp2f(v); }

// packed f32x2 -> bf16x2 (RNE), 1 instruction
__device__ __forceinline__ unsigned pkbf(float lo, float hi) {
    unsigned r;
    asm("v_cvt_pk_bf16_f32 %0, %1, %2" : "=v"(r) : "v"(lo), "v"(hi));
    return r;
}

// LSTM cell with combined reciprocals (3 rcp instead of 5).
// Gates pre-scaled: i,f,o by log2e; g by 2*log2e.
//   i*g        = (B-1)/((1+A)(1+B)),  A=2^-si, B=2^sg
//   o*tanh(c') = (D-1)/((1+C)(1+D)),  C=2^-so, D=2^(2*log2e*c')
__device__ __forceinline__ float cell_h(const f32x4 a, float& cst) {
    float A  = fexp2(-a[0]);
    float Bv = fexp2(a[2]);
    float rf = frcp(1.0f + fexp2(-a[1]));
    float ig = (Bv - 1.0f) * frcp((1.0f + A) * (1.0f + Bv));
    cst = fmaf(cst, rf, ig);
    float C  = fexp2(-a[3]);
    float D  = fexp2(2.0f * LOG2E * cst);
    return (D - 1.0f) * frcp((1.0f + C) * (1.0f + D));
}

// raw barrier: drains LDS (lgkmcnt) only -- NOT vmcnt -- so prefetched global
// loads stay in flight across the per-step barriers.
#define BAR() asm volatile("s_waitcnt lgkmcnt(0)\n\ts_barrier" ::: "memory")

#define MFMA __builtin_amdgcn_mfma_f32_16x16x32_bf16

// z^T = Wt[256 gate-rows x 96] @ hx^T[96 x 16 rows].  Wave w (0..3) owns
// gate-row tiles 4w..4w+3 (units 16w..16w+15); B-frags are read ONCE per wave
// and shared across its 4 tiles.  Gate-row packing within tile t: local row
// r = q*4+g -> unit = (t>>1)*8 + q*2 + (t&1), gate = g.
// Per lane (q,m), tile i: unit u_i = 16w + (i>>1)*8 + q*2 + (i&1)
//   -> tiles 0,1 and 2,3 give ADJACENT units: two packed b32 h-writes.
// A-frag: lane l holds A[m=l&15][k=(l>>4)*8+j] (static pre-scaled weights in VGPRs)
// B-frag: lane l holds B[k=(l>>4)*8+j][n=l&15] (hb/xs reads)
// C/D:    lane l holds D[row=q*4+reg][col=m]   (4 gates of one cell per lane)
__global__ __launch_bounds__(NTHR, 1)
void lstm_v9(const float* __restrict__ x,
             const float* __restrict__ W1, const float* __restrict__ U1, const float* __restrict__ b1,
             const float* __restrict__ W2, const float* __restrict__ U2, const float* __restrict__ b2,
             const float* __restrict__ Wd, const float* __restrict__ bd,
             float* __restrict__ out)
{
    __shared__ __align__(16) short hb[2][ROWS][HBS];     // bf16 h, ping-pong
    __shared__ __align__(16) short xs[CHUNK][ROWS][HBS]; // bf16 x chunk; plane 0 = preds in decode
    __shared__ float WdL[Udim * Fdim];                   // dense weights, fp32

    const int tid = threadIdx.x;
    const int l   = tid & 63;
    const int w   = tid >> 6;         // wave 0..3
    const int q   = l >> 4;
    const int m   = l & 15;
    const int brow = blockIdx.x * ROWS;

    // ---- prefetch chunk 0 of x into registers (hide HBM latency under weight staging) ----
    const int f4 = tid & 7;           // float4 column 0..7
    const int xrow = (tid >> 3) & 15; // batch row
    const int tb = tid >> 7;          // base step 0/1; steps tb + 2i
    float4 pf[8];
#pragma unroll
    for (int i = 0; i < 8; ++i)
        pf[i] = *(const float4*)&x[((size_t)(brow + xrow) * T_STEPS + (tb + 2 * i)) * Fdim + f4 * 4];

    // ---- stage both weight sets as register-resident A-fragments (pre-scaled) ----
    short8 wa1[4][3], wa2[4][3];
    f32x4 bs1[4], bs2[4];
#pragma unroll
    for (int i = 0; i < 4; ++i) {
        const int unit_a = 16 * w + (i >> 1) * 8 + (m >> 2) * 2 + (i & 1); // A-row m -> (unit, gate)
        const int gate_a = m & 3;
        const int col = gate_a * 64 + unit_a;          // column in original [4U] layout
        const float sA = (gate_a == 2) ? 2.0f * LOG2E : LOG2E;
#pragma unroll
        for (int kt = 0; kt < 3; ++kt) {
            short8 fa, fb;
#pragma unroll
            for (int j = 0; j < 8; ++j) {
                const int k = kt * 32 + q * 8 + j;
                float v1 = (k < Udim) ? U1[k * G4 + col] : W1[(k - Udim) * G4 + col];
                float v2 = (k < Udim) ? U2[k * G4 + col] : W2[(k - Udim) * G4 + col];
                fa[j] = f2bf(v1 * sA);
                fb[j] = f2bf(v2 * sA);
            }
            wa1[i][kt] = fa;
            wa2[i][kt] = fb;
        }
        const int unit_d = 16 * w + (i >> 1) * 8 + q * 2 + (i & 1); // D rows q*4+g -> unit_d, gate=g
#pragma unroll
        for (int g = 0; g < 4; ++g) {
            const float sD = (g == 2) ? 2.0f * LOG2E : LOG2E;
            bs1[i][g] = b1[g * 64 + unit_d] * sD;
            bs2[i][g] = b2[g * 64 + unit_d] * sD;
        }
    }

    const int hw0 = 16 * w + q * 2;   // packed h write (tiles 0,1) -> even short index
    const int hw1 = hw0 + 8;          // packed h write (tiles 2,3)
    const int sr = tid >> 4;          // dense: row 0..15
    const int sc = tid & 15;          // dense: cols sc, sc+16
    const float bdv0 = bd[sc], bdv1 = bd[sc + 16];

    for (int idx = tid; idx < 2 * ROWS * HBS; idx += NTHR) ((short*)hb)[idx] = 0;
    for (int idx = tid; idx < Udim * Fdim; idx += NTHR) WdL[idx] = Wd[idx];
    float cst0 = 0.f, cst1 = 0.f, cst2 = 0.f, cst3 = 0.f;

    // ================= warmup: 16 chunks x 16 steps, 1 raw barrier/step =================
    for (int c = 0; c < NCHUNK; ++c) {
        // convert prefetched chunk to bf16 and stage
#pragma unroll
        for (int i = 0; i < 8; ++i) {
            uint2 pk;
            pk.x = pkbf(pf[i].x, pf[i].y);
            pk.y = pkbf(pf[i].z, pf[i].w);
            *(uint2*)&xs[tb + 2 * i][xrow][f4 * 4] = pk;
        }
        // issue next chunk's loads; they stay in flight across all 16 step barriers
        if (c + 1 < NCHUNK) {
#pragma unroll
            for (int i = 0; i < 8; ++i)
                pf[i] = *(const float4*)&x[((size_t)(brow + xrow) * T_STEPS + ((c + 1) * CHUNK + tb + 2 * i)) * Fdim + f4 * 4];
        }
        BAR();                        // xs (and, for c=0, hb-init) visible

        // x B-frag for step 0 of this chunk (xs stable within the chunk:
        // each step prefetches the NEXT step's x-frag before its barrier)
        short8 b2p = *(const short8*)&xs[0][m][q * 8];

#pragma unroll 2
        for (int t2 = 0; t2 < CHUNK; ++t2) {
            const int p = t2 & 1;     // c*16 even -> parity continues across chunks

            const short8 b2v = b2p;
            const short8 b0  = *(const short8*)&hb[p][m][q * 8];
            const short8 b1v = *(const short8*)&hb[p][m][32 + q * 8];

            // x-MFMAs first: operands in regs -> issue at barrier release,
            // covering the h-frag ds_read latency
            f32x4 a0 = MFMA(wa1[0][2], b2v, bs1[0], 0, 0, 0);
            f32x4 a1 = MFMA(wa1[1][2], b2v, bs1[1], 0, 0, 0);
            f32x4 a2 = MFMA(wa1[2][2], b2v, bs1[2], 0, 0, 0);
            f32x4 a3 = MFMA(wa1[3][2], b2v, bs1[3], 0, 0, 0);
            a0 = MFMA(wa1[0][0], b0, a0, 0, 0, 0);
            a1 = MFMA(wa1[1][0], b0, a1, 0, 0, 0);
            a2 = MFMA(wa1[2][0], b0, a2, 0, 0, 0);
            a3 = MFMA(wa1[3][0], b0, a3, 0, 0, 0);
            a0 = MFMA(wa1[0][1], b1v, a0, 0, 0, 0);
            a1 = MFMA(wa1[1][1], b1v, a1, 0, 0, 0);
            a2 = MFMA(wa1[2][1], b1v, a2, 0, 0, 0);
            a3 = MFMA(wa1[3][1], b1v, a3, 0, 0, 0);

            const float h0 = cell_h(a0, cst0);
            const float h1 = cell_h(a1, cst1);
            const float h2 = cell_h(a2, cst2);
            const float h3 = cell_h(a3, cst3);
            *(unsigned*)&hb[1 - p][m][hw0] = pkbf(h0, h1);
            *(unsigned*)&hb[1 - p][m][hw1] = pkbf(h2, h3);
            if (t2 + 1 < CHUNK)
                b2p = *(const short8*)&xs[t2 + 1][m][q * 8];
            BAR();                    // doubles as pre-stage barrier for next chunk
        }
    }

    // ================= pred0 = h @ Wd + bd (h in hb[0]) =================
    short8 b0p, b1p;
    {
        float acc0 = bdv0, acc1 = bdv1;
#pragma unroll
        for (int kb = 0; kb < 8; ++kb) {
            short8 h8 = *(const short8*)&hb[0][sr][kb * 8];
#pragma unroll
            for (int j = 0; j < 8; ++j) {
                const float hf = bf2f(h8[j]);
                acc0 = fmaf(hf, WdL[(kb * 8 + j) * Fdim + sc], acc0);
                acc1 = fmaf(hf, WdL[(kb * 8 + j) * Fdim + sc + 16], acc1);
            }
        }
        out[(size_t)(brow + sr) * (OUT_STEPS * Fdim) + sc] = acc0;
        out[(size_t)(brow + sr) * (OUT_STEPS * Fdim) + sc + 16] = acc1;
        xs[0][sr][sc] = f2bf(acc0);       // pred buffer = xs plane 0
        xs[0][sr][sc + 16] = f2bf(acc1);
        // prefetch decode h-frags (hb[0] is final)
        b0p = *(const short8*)&hb[0][m][q * 8];
        b1p = *(const short8*)&hb[0][m][32 + q * 8];
    }
    BAR();

    // ================= decode: 23 steps of LSTM2 + dense =================
    int dp = 0;
    for (int s = 1; s < OUT_STEPS; ++s) {
        // pred read is the only fresh LDS dependency; h-frags were prefetched
        const short8 b2v = *(const short8*)&xs[0][m][q * 8];

        f32x4 a0 = MFMA(wa2[0][0], b0p, bs2[0], 0, 0, 0);
        f32x4 a1 = MFMA(wa2[1][0], b0p, bs2[1], 0, 0, 0);
        f32x4 a2 = MFMA(wa2[2][0], b0p, bs2[2], 0, 0, 0);
        f32x4 a3 = MFMA(wa2[3][0], b0p, bs2[3], 0, 0, 0);
        a0 = MFMA(wa2[0][1], b1p, a0, 0, 0, 0);
        a1 = MFMA(wa2[1][1], b1p, a1, 0, 0, 0);
        a2 = MFMA(wa2[2][1], b1p, a2, 0, 0, 0);
        a3 = MFMA(wa2[3][1], b1p, a3, 0, 0, 0);
        a0 = MFMA(wa2[0][2], b2v, a0, 0, 0, 0);
        a1 = MFMA(wa2[1][2], b2v, a1, 0, 0, 0);
        a2 = MFMA(wa2[2][2], b2v, a2, 0, 0, 0);
        a3 = MFMA(wa2[3][2], b2v, a3, 0, 0, 0);

        const float h0 = cell_h(a0, cst0);
        const float h1 = cell_h(a1, cst1);
        const float h2 = cell_h(a2, cst2);
        const float h3 = cell_h(a3, cst3);
        *(unsigned*)&hb[1 - dp][m][hw0] = pkbf(h0, h1);
        *(unsigned*)&hb[1 - dp][m][hw1] = pkbf(h2, h3);
        BAR();                        // h ready for dense

        {
            float acc0 = bdv0, acc1 = bdv1;
#pragma unroll
            for (int kb = 0; kb < 8; ++kb) {
                short8 h8 = *(const short8*)&hb[1 - dp][sr][kb * 8];
#pragma unroll
                for (int j = 0; j < 8; ++j) {
                    const float hf = bf2f(h8[j]);
                    acc0 = fmaf(hf, WdL[(kb * 8 + j) * Fdim + sc], acc0);
                    acc1 = fmaf(hf, WdL[(kb * 8 + j) * Fdim + sc + 16], acc1);
                }
            }
            out[(size_t)(brow + sr) * (OUT_STEPS * Fdim) + s * Fdim + sc] = acc0;
            out[(size_t)(brow + sr) * (OUT_STEPS * Fdim) + s * Fdim + sc + 16] = acc1;
            xs[0][sr][sc] = f2bf(acc0);       // pred feedback
            xs[0][sr][sc + 16] = f2bf(acc1);
        }
        // prefetch next step's h-frags (hb[1-dp] is final after BAR above)
        b0p = *(const short8*)&hb[1 - dp][m][q * 8];
        b1p = *(const short8*)&hb[1 - dp][m][32 + q * 8];
        BAR();
        dp = 1 - dp;
    }
}

extern "C" void kernel_launch(void* const* d_in, const int* in_sizes, int n_in,
                              void* d_out, int out_size, void* d_ws, size_t ws_size,
                              hipStream_t stream) {
    (void)in_sizes; (void)n_in; (void)out_size; (void)d_ws; (void)ws_size;
    const float* x  = (const float*)d_in[0];
    const float* W1 = (const float*)d_in[1];
    const float* U1 = (const float*)d_in[2];
    const float* b1 = (const float*)d_in[3];
    const float* W2 = (const float*)d_in[4];
    const float* U2 = (const float*)d_in[5];
    const float* b2 = (const float*)d_in[6];
    const float* Wd = (const float*)d_in[7];
    const float* bd = (const float*)d_in[8];
    float* out = (float*)d_out;

    lstm_v9<<<dim3(NBLK), dim3(NTHR), 0, stream>>>(
        x, W1, U1, b1, W2, U2, b2, Wd, bd, out);
}

// Round 5
// 277.532 us; speedup vs baseline: 1.2289x; 1.2289x over previous
//
#include <hip/hip_runtime.h>
#include <math.h>

#define T_STEPS 256
#define Fdim 32
#define Udim 64
#define G4 256            // 4*U
#define OUT_STEPS 24
#define ROWS 16           // batch rows per block (= MFMA N)
#define NBLK 256          // 4096 / 16
#define NTHR 512          // 8 waves, 2 waves/SIMD: measured-best partition (v6=168 vs v8=191, v9=205)
#define HBS 72            // row stride in shorts (144 B, 36 dwords: measured-best layout)
#define CHUNK 16
#define NCHUNK 16         // 16 * 16 = 256 steps
#define LOG2E 1.4426950408889634f

typedef __attribute__((ext_vector_type(8))) short short8;   // 8 bf16 = 4 VGPR
typedef __attribute__((ext_vector_type(4))) float f32x4;

__device__ __forceinline__ short f2bf(float f) {
    union { float f; unsigned u; } v; v.f = f;
    unsigned r = v.u + 0x7FFFu + ((v.u >> 16) & 1u);   // RNE
    return (short)(r >> 16);
}
__device__ __forceinline__ float bf2f(short s) {
    union { unsigned u; float f; } v; v.u = ((unsigned)(unsigned short)s) << 16;
    return v.f;
}
__device__ __forceinline__ float frcp(float v) { return __builtin_amdgcn_rcpf(v); }
__device__ __forceinline__ float fexp2(float v) { return __builtin_amdgcn_exp2f(v); }

// packed f32x2 -> bf16x2 (RNE), 1 instruction
__device__ __forceinline__ unsigned pkbf(float lo, float hi) {
    unsigned r;
    asm("v_cvt_pk_bf16_f32 %0, %1, %2" : "=v"(r) : "v"(lo), "v"(hi));
    return r;
}

// LSTM cell with combined reciprocals (3 rcp instead of 5).
// Gates pre-scaled: i,f,o by log2e; g by 2*log2e.
//   i*g        = (B-1)/((1+A)(1+B)),  A=2^-si, B=2^sg
//   o*tanh(c') = (D-1)/((1+C)(1+D)),  C=2^-so, D=2^(2*log2e*c')
__device__ __forceinline__ float cell_h(const f32x4 a, float& cst) {
    float A  = fexp2(-a[0]);
    float Bv = fexp2(a[2]);
    float rf = frcp(1.0f + fexp2(-a[1]));
    float ig = (Bv - 1.0f) * frcp((1.0f + A) * (1.0f + Bv));
    cst = fmaf(cst, rf, ig);
    float C  = fexp2(-a[3]);
    float D  = fexp2(2.0f * LOG2E * cst);
    return (D - 1.0f) * frcp((1.0f + C) * (1.0f + D));
}

// raw barrier: drains LDS (lgkmcnt) only -- NOT vmcnt -- so prefetched global
// loads stay in flight across the per-step barriers.
#define BAR() asm volatile("s_waitcnt lgkmcnt(0)\n\ts_barrier" ::: "memory")

#define MFMA __builtin_amdgcn_mfma_f32_16x16x32_bf16

// z^T = Wt[256 gate-rows x 96] @ hx^T[96 x 16 rows], tile t covers gate-rows t*16..t*16+15.
// Wave w (0..7) owns tiles 2w, 2w+1 -> lane (q,m) owns cells (units w*8+q*2, w*8+q*2+1; row m)
// A-frag: lane l holds A[m=l&15][k=(l>>4)*8+j] (static pre-scaled weights in VGPRs)
// B-frag: lane l holds B[k=(l>>4)*8+j][n=l&15] (hb reads; x-frags register-resident per chunk)
// C/D:    lane l holds D[row=q*4+reg][col=m]   (4 gates of one cell per lane)
// Dense (pred = h @ Wd + bd) as MFMA on waves 0,1: tile t=w covers pred-cols 16w..16w+15,
// Wd split hi/lo bf16 (4 MFMAs) for fp32-level accuracy on the direct output.
__global__ __launch_bounds__(NTHR, 2)
void lstm_v10(const float* __restrict__ x,
              const float* __restrict__ W1, const float* __restrict__ U1, const float* __restrict__ b1,
              const float* __restrict__ W2, const float* __restrict__ U2, const float* __restrict__ b2,
              const float* __restrict__ Wd, const float* __restrict__ bd,
              float* __restrict__ out)
{
    __shared__ __align__(16) short hb[2][ROWS][HBS];     // bf16 h, ping-pong
    __shared__ __align__(16) short xs[CHUNK][ROWS][HBS]; // bf16 x chunk; plane 0 = preds in decode

    const int tid = threadIdx.x;
    const int l   = tid & 63;
    const int w   = tid >> 6;         // wave 0..7
    const int q   = l >> 4;
    const int m   = l & 15;
    const int brow = blockIdx.x * ROWS;

    // ---- prefetch chunk 0 of x into registers (hide HBM latency under weight staging) ----
    const int f4  = tid & 7;          // float4 column 0..7
    const int tt  = (tid >> 3) & 15;  // step within chunk
    const int xr0 = tid >> 7;         // base row 0..3; rows xr0+4i
    float4 pf[4];
#pragma unroll
    for (int i = 0; i < 4; ++i)
        pf[i] = *(const float4*)&x[((size_t)(brow + xr0 + 4 * i) * T_STEPS + tt) * Fdim + f4 * 4];

    // ---- stage both LSTM weight sets as register-resident A-fragments (pre-scaled) ----
    short8 wa1[2][3], wa2[2][3];
    f32x4 bs1[2], bs2[2];
#pragma unroll
    for (int nt = 0; nt < 2; ++nt) {
        const int unit_a = w * 8 + (m >> 2) * 2 + nt;  // A-row m -> (unit, gate)
        const int gate_a = m & 3;
        const int col = gate_a * 64 + unit_a;          // column in original [4U] layout
        const float sA = (gate_a == 2) ? 2.0f * LOG2E : LOG2E;
#pragma unroll
        for (int kt = 0; kt < 3; ++kt) {
            short8 fa, fb;
#pragma unroll
            for (int j = 0; j < 8; ++j) {
                const int k = kt * 32 + q * 8 + j;
                float v1 = (k < Udim) ? U1[k * G4 + col] : W1[(k - Udim) * G4 + col];
                float v2 = (k < Udim) ? U2[k * G4 + col] : W2[(k - Udim) * G4 + col];
                fa[j] = f2bf(v1 * sA);
                fb[j] = f2bf(v2 * sA);
            }
            wa1[nt][kt] = fa;
            wa2[nt][kt] = fb;
        }
        const int unit_d = w * 8 + q * 2 + nt;         // D rows q*4+g -> unit_d, gate=g
#pragma unroll
        for (int g = 0; g < 4; ++g) {
            const float sD = (g == 2) ? 2.0f * LOG2E : LOG2E;
            bs1[nt][g] = b1[g * 64 + unit_d] * sD;
            bs2[nt][g] = b2[g * 64 + unit_d] * sD;
        }
    }

    // ---- dense weights as hi/lo bf16 A-fragments (tile = wave 0 or 1) ----
    short8 wdh[2], wdlo[2];
    f32x4 bdC;
    {
        const int wsel = (w < 2) ? w : 0;              // avoid OOB for unused waves
#pragma unroll
        for (int kt = 0; kt < 2; ++kt) {
            short8 fh, fl;
#pragma unroll
            for (int j = 0; j < 8; ++j) {
                const float v = Wd[(kt * 32 + q * 8 + j) * Fdim + 16 * wsel + m];
                const short hi = f2bf(v);
                fh[j] = hi;
                fl[j] = f2bf(v - bf2f(hi));
            }
            wdh[kt] = fh;
            wdlo[kt] = fl;
        }
#pragma unroll
        for (int g = 0; g < 4; ++g) bdC[g] = bd[16 * wsel + q * 4 + g];
    }

    const int hw = w * 8 + q * 2;     // packed h write index (even)
    for (int idx = tid; idx < 2 * ROWS * HBS; idx += NTHR) ((short*)hb)[idx] = 0;
    float cst[2] = {0.f, 0.f};

    // ================= warmup: 16 chunks x 16 steps, 1 raw barrier/step =================
    for (int c = 0; c < NCHUNK; ++c) {
        // convert prefetched chunk to bf16 and stage
#pragma unroll
        for (int i = 0; i < 4; ++i) {
            uint2 pk;
            pk.x = pkbf(pf[i].x, pf[i].y);
            pk.y = pkbf(pf[i].z, pf[i].w);
            *(uint2*)&xs[tt][xr0 + 4 * i][f4 * 4] = pk;
        }
        // issue next chunk's loads; they stay in flight across all 16 step barriers
        if (c + 1 < NCHUNK) {
#pragma unroll
            for (int i = 0; i < 4; ++i)
                pf[i] = *(const float4*)&x[((size_t)(brow + xr0 + 4 * i) * T_STEPS + ((c + 1) * CHUNK + tt)) * Fdim + f4 * 4];
        }
        BAR();                        // xs (and, for c=0, hb-init) visible

        // burst-read the whole chunk's x B-frags into registers: removes the
        // per-step xs read from the post-barrier critical path (v8 showed the
        // per-step LDS burst is ~fully serial on step time)
        short8 xf[CHUNK];
#pragma unroll
        for (int t = 0; t < CHUNK; ++t)
            xf[t] = *(const short8*)&xs[t][m][q * 8];

#pragma unroll
        for (int t2 = 0; t2 < CHUNK; ++t2) {
            const int p = t2 & 1;     // c*16 even -> parity continues across chunks

            const short8 b0  = *(const short8*)&hb[p][m][q * 8];
            const short8 b1v = *(const short8*)&hb[p][m][32 + q * 8];

            // x-MFMAs first: operands already in regs -> issue at barrier release,
            // covering the h-frag ds_read latency
            f32x4 a0 = MFMA(wa1[0][2], xf[t2], bs1[0], 0, 0, 0);
            f32x4 a1 = MFMA(wa1[1][2], xf[t2], bs1[1], 0, 0, 0);
            a0 = MFMA(wa1[0][0], b0, a0, 0, 0, 0);
            a1 = MFMA(wa1[1][0], b0, a1, 0, 0, 0);
            a0 = MFMA(wa1[0][1], b1v, a0, 0, 0, 0);
            a1 = MFMA(wa1[1][1], b1v, a1, 0, 0, 0);

            const float h0 = cell_h(a0, cst[0]);
            const float h1 = cell_h(a1, cst[1]);
            *(unsigned*)&hb[1 - p][m][hw] = pkbf(h0, h1);
            BAR();                    // doubles as pre-stage barrier for next chunk
        }
    }

    // ================= pred0 = h @ Wd + bd via MFMA (h in hb[0]) =================
    short8 b0p = *(const short8*)&hb[0][m][q * 8];
    short8 b1p = *(const short8*)&hb[0][m][32 + q * 8];
    if (w < 2) {
        f32x4 pz = MFMA(wdh[0], b0p, bdC, 0, 0, 0);
        pz = MFMA(wdh[1], b1p, pz, 0, 0, 0);
        pz = MFMA(wdlo[0], b0p, pz, 0, 0, 0);
        pz = MFMA(wdlo[1], b1p, pz, 0, 0, 0);
        *(f32x4*)&out[(size_t)(brow + m) * (OUT_STEPS * Fdim) + 16 * w + q * 4] = pz;
        uint2 fp;
        fp.x = pkbf(pz[0], pz[1]);
        fp.y = pkbf(pz[2], pz[3]);
        *(uint2*)&xs[0][m][16 * w + q * 4] = fp;       // pred buffer = xs plane 0
    }
    BAR();

    // ================= decode: 23 steps of LSTM2 + MFMA dense =================
    int dp = 0;
    for (int s = 1; s < OUT_STEPS; ++s) {
        // pred read is the only fresh LDS dependency; h-frags were prefetched
        const short8 b2v = *(const short8*)&xs[0][m][q * 8];

        f32x4 a0 = MFMA(wa2[0][0], b0p, bs2[0], 0, 0, 0);
        f32x4 a1 = MFMA(wa2[1][0], b0p, bs2[1], 0, 0, 0);
        a0 = MFMA(wa2[0][1], b1p, a0, 0, 0, 0);
        a1 = MFMA(wa2[1][1], b1p, a1, 0, 0, 0);
        a0 = MFMA(wa2[0][2], b2v, a0, 0, 0, 0);
        a1 = MFMA(wa2[1][2], b2v, a1, 0, 0, 0);

        const float h0 = cell_h(a0, cst[0]);
        const float h1 = cell_h(a1, cst[1]);
        *(unsigned*)&hb[1 - dp][m][hw] = pkbf(h0, h1);
        BAR();                        // h ready

        // prefetch next step's h-frags (used by dense now AND LSTM next step)
        b0p = *(const short8*)&hb[1 - dp][m][q * 8];
        b1p = *(const short8*)&hb[1 - dp][m][32 + q * 8];
        if (w < 2) {
            f32x4 pz = MFMA(wdh[0], b0p, bdC, 0, 0, 0);
            pz = MFMA(wdh[1], b1p, pz, 0, 0, 0);
            pz = MFMA(wdlo[0], b0p, pz, 0, 0, 0);
            pz = MFMA(wdlo[1], b1p, pz, 0, 0, 0);
            *(f32x4*)&out[(size_t)(brow + m) * (OUT_STEPS * Fdim) + s * Fdim + 16 * w + q * 4] = pz;
            uint2 fp;
            fp.x = pkbf(pz[0], pz[1]);
            fp.y = pkbf(pz[2], pz[3]);
            *(uint2*)&xs[0][m][16 * w + q * 4] = fp;   // pred feedback
        }
        BAR();
        dp = 1 - dp;
    }
}

extern "C" void kernel_launch(void* const* d_in, const int* in_sizes, int n_in,
                              void* d_out, int out_size, void* d_ws, size_t ws_size,
                              hipStream_t stream) {
    (void)in_sizes; (void)n_in; (void)out_size; (void)d_ws; (void)ws_size;
    const float* x  = (const float*)d_in[0];
    const float* W1 = (const float*)d_in[1];
    const float* U1 = (const float*)d_in[2];
    const float* b1 = (const float*)d_in[3];
    const float* W2 = (const float*)d_in[4];
    const float* U2 = (const float*)d_in[5];
    const float* b2 = (const float*)d_in[6];
    const float* Wd = (const float*)d_in[7];
    const float* bd = (const float*)d_in[8];
    float* out = (float*)d_out;

    lstm_v10<<<dim3(NBLK), dim3(NTHR), 0, stream>>>(
        x, W1, U1, b1, W2, U2, b2, Wd, bd, out);
}